// Round 9
// baseline (41.331 us; speedup 1.0000x reference)
//
#include <hip/hip_runtime.h>
#include <hip/hip_bf16.h>

#define HW 3136     // 56*56
#define CC 256
#define MM 72       // K*K*G (real)
#define HH 56
#define WW 56

typedef __attribute__((ext_vector_type(8))) short short8;   // 8 bf16 (4 VGPR)
typedef __attribute__((ext_vector_type(4))) float f32x4;    // MFMA acc / float4

#define WAITVM(n) asm volatile("s_waitcnt vmcnt(" #n ")" ::: "memory")
#define LGKM0     asm volatile("s_waitcnt lgkmcnt(0)" ::: "memory")
#define CFENCE    asm volatile("" ::: "memory")   // pin VM-op program order

__device__ __forceinline__ void blockbar() {
    CFENCE;
    __builtin_amdgcn_s_barrier();     // raw barrier: NO auto vmcnt(0) drain
    CFENCE;
}

__device__ inline unsigned short f2b(float f) {
    unsigned u; __builtin_memcpy(&u, &f, 4);
    unsigned r = u + 0x7fffu + ((u >> 16) & 1u);   // RNE to bf16
    return (unsigned short)(r >> 16);
}
__device__ inline float b2f(unsigned short s) {
    unsigned u = ((unsigned)s) << 16; float f; __builtin_memcpy(&f, &u, 4);
    return f;
}
__device__ __forceinline__ float asf(unsigned u) {
    float f; __builtin_memcpy(&f, &u, 4); return f;
}
// packed fp32x2 -> bf16x2 (RNE, same rounding as f2b); no builtin (m240) -> asm
__device__ __forceinline__ unsigned cvtpk(float lo, float hi) {
    unsigned r;
    asm("v_cvt_pk_bf16_f32 %0, %1, %2" : "=v"(r) : "v"(lo), "v"(hi));
    return r;
}

// fire-and-forget 16B global -> LDS DMA (counted in vmcnt; LDS dst is
// wave-uniform base + lane*16)
__device__ __forceinline__ void gl2lds16(const float* g, float* l) {
    __builtin_amdgcn_global_load_lds(
        (const __attribute__((address_space(1))) void*)g,
        (__attribute__((address_space(3))) void*)l, 16, 0, 0);
}

// ---------------------------------------------------------------------------
// k0: fold the two 1x1 convs into bf16 W [80][256] (rows 72..95 zero) and
// fp32 bias [80]. (verified, unchanged)
// ---------------------------------------------------------------------------
__global__ __launch_bounds__(256) void k0_combine(
    const float* __restrict__ w_reduce,   // [128][256]
    const float* __restrict__ b_reduce,   // [128]
    const float* __restrict__ w_span,     // [72][128]
    const float* __restrict__ b_span,     // [72]
    unsigned short* __restrict__ wbf,     // [80][256] bf16
    float* __restrict__ bcomb)            // [80]
{
    __shared__ float red[4][64];
    __shared__ float redb[256];

    const int m  = blockIdx.x;       // 0..79
    const int cq = blockIdx.y;       // 0..3
    const int t  = threadIdx.x;
    const int oq = t >> 6;           // o-chunk (wave id)
    const int cl = t & 63;
    const int c  = cq * 64 + cl;

    float acc = 0.f;
    if (m < MM) {
        const float* wsB = w_span   + m * 128 + oq * 32;
        const float* wrB = w_reduce + (size_t)(oq * 32) * 256 + c;
#pragma unroll 8
        for (int o = 0; o < 32; ++o)
            acc = fmaf(wsB[o], wrB[(size_t)o * 256], acc);
    }
    if (oq != 0) red[oq][cl] = acc;
    __syncthreads();
    if (oq == 0)
        wbf[m * 256 + c] = f2b(acc + red[1][cl] + red[2][cl] + red[3][cl]);

    if (cq == 0) {   // uniform per block -> safe to sync inside
        redb[t] = (m < MM && t < 128) ? w_span[m * 128 + t] * b_reduce[t] : 0.f;
        __syncthreads();
#pragma unroll
        for (int s2 = 128; s2 > 0; s2 >>= 1) {
            if (t < s2) redb[t] += redb[t + s2];
            __syncthreads();
        }
        if (t == 0) bcomb[m] = (m < MM ? b_span[m] : 0.f) + redb[0];
    }
}

// ---------------------------------------------------------------------------
// k_fused (persistent-bf16 design):
//  - xper[256 ch][6 rows][36] bf16 (110.6 KB): the ENTIRE haloed x tile,
//    staged ONCE via reg-path (global f32x4 -> cvt_pk -> ds_write_b64).
//    idx = col - c0 + 4 (cols c0-4..c0+31 clamped; masked taps cover edges).
//  - A section: 8 GEMM phases. bq read as 8x ds_read_u16 from xper (same
//    bf16 RNE values as the old f2b path -> GEMM bit-identical). aq from a
//    ring-3 W slot [72][32] (verified XOR layout); m>=72 lanes read a shared
//    zero-quad. ker -> kl LDS (verbatim).
//  - B section: FREE-RUNNING. No DMA, no barriers, no vmcnt. Per chunk:
//    taps from kl, x window from xper (u16 + b64 + u16 per row), 36 FMA,
//    f32x4 store. Only numerics change vs verified: x operand is bf16.
//
// Reg-staging ledger (XL = 4 plain loads waves0-5 / 3 wave6; WD = 1 DMA
// waves0-4 / 0 else; order pinned by CFENCE; audited per wave):
//   prologue XL0,WD0,XL1,WD1 -> wait 5 / 4 / 3; CW0; XL2; bar
//   phase s (tail, s<6): wait 4 / 4 / 3  (leaves XL(s+2) in flight)
//               s==6  : wait 0 (one-time tail drain)
//   phase s tail: CW(s+1); WD(s+2) [s<=5]; XL(s+3) [s<=4]; lgkm0; bar
// grid(448 = 8*56 XCD swizzle), block(448). LDS 140560 B -> 1 blk/CU.
// ---------------------------------------------------------------------------
__global__ __launch_bounds__(448) void k_fused(
    const float* __restrict__ x,              // [16][256][3136] fp32
    const unsigned short* __restrict__ wbf,   // [80][256] bf16
    const float* __restrict__ bcomb,          // [80]
    float* __restrict__ out)                  // [16][256][3136] fp32
{
    __shared__ __align__(16) unsigned short xper[256 * 216];   // 110592 B
    __shared__ __align__(16) unsigned short wsl[3][2304];      // 13824 B
    __shared__ __align__(16) unsigned short kl[MM * 112];      // 16128 B
    __shared__ __align__(16) unsigned short wz[8];             // 16 B zero-quad

    const int L   = blockIdx.x;               // 0..447
    const int wk  = (L & 7) * 56 + (L >> 3);  // bijective (448 = 8*56)
    const int b   = wk / 28;
    const int rem = wk - b * 28;
    const int ht  = rem >> 1;                 // 0..13
    const int cs  = rem & 1;                  // column half
    const int h0  = ht * 4;
    const int c0  = cs * 28;

    const int t    = threadIdx.x;             // 0..447
    const int lane = t & 63;
    const int wv   = t >> 6;                  // wave 0..6 = GEMM n-tile
    const int l15  = lane & 15;
    const int q    = lane >> 4;

    const int chh   = t / 28;                 // 0..15  (B: channel in chunk)
    const int rem28 = t - chh * 28;
    const int rA    = rem28 / 7;              // out row in band
    const int qA    = rem28 - rA * 7;         // 4-col strip

    const float* xb = x + (size_t)b * CC * HW;

    // ---- GEMM per-thread constants ----
    const int nb    = wv * 16 + l15;               // GEMM n = tile px (0..111)
    const int rApx  = nb / 28;
    const int colr  = nb - rApx * 28;
    const int bqoff = (rApx + 1) * 36 + colr + 4;  // xper offset of px (core row)
    const int swA   = (l15 ^ (l15 >> 2)) & 3;      // A-frag XOR swizzle
    const int aBo2  = (q ^ swA) * 8;               // A-frag k-group offset
    const int wswr  = ((t >> 2) ^ (t >> 4)) & 3;   // wbf pre-swizzled source
    const unsigned short* wsrc0 = wbf + (t >> 2) * 256 + ((t & 3) ^ wswr) * 8;

    // ---- x staging maps: per phase 32 ch x 6 r x 9 quads = 1728 quads;
    //      thread does i=0..2 always, i==3 iff t<384 (waves 0-5) ----
    int xqoff[4], xdst[4];
#pragma unroll
    for (int i = 0; i < 4; ++i) {
        int f = i * 448 + t; if (f > 1727) f = 1727;     // wave-6 i=3 unused
        const int ch_l = f / 54;
        const int r2   = f - ch_l * 54;
        const int r    = r2 / 9;                         // stage row 0..5
        const int qd   = r2 - r * 9;                     // quad 0..8
        const int hh   = h0 - 1 + r;
        const int hc   = hh < 0 ? 0 : (hh > 55 ? 55 : hh);
        int colc = c0 - 4 + 4 * qd;                      // clamp keeps 16B-aligned
        colc = colc < 0 ? 0 : (colc > 52 ? 52 : colc);
        xqoff[i] = ch_l * HW + hc * WW + colc;
        xdst[i]  = ch_l * 216 + r * 36 + qd * 4;         // shorts; 8B-aligned
    }

    // ---- apply masks (verbatim) ----
    float vmm[3];
#pragma unroll
    for (int kh = 0; kh < 3; ++kh) {
        const int row = h0 + rA - 1 + kh;
        vmm[kh] = (row >= 0 && row < HH) ? 1.f : 0.f;
    }
    const float lm  = (cs == 0 && qA == 0) ? 0.f : 1.f;   // w-1 < 0
    const float rmm = (cs == 1 && qA == 6) ? 0.f : 1.f;   // w+4 > 55

    // ---- stage helpers ----
    f32x4 ra[4], rb[4];
    auto xl = [&](int s, f32x4* R) {          // plain global loads -> regs
        const float* sp = xb + (size_t)(s * 32) * HW;
#pragma unroll
        for (int i = 0; i < 4; ++i)
            if (i < 3 || t < 384) R[i] = *(const f32x4*)(sp + xqoff[i]);
    };
    auto cw = [&](int s, const f32x4* R) {    // cvt + ds_write_b64 into xper
        unsigned short* xd = xper + s * (32 * 216);
#pragma unroll
        for (int i = 0; i < 4; ++i)
            if (i < 3 || t < 384) {
                uint2 w; w.x = cvtpk(R[i].x, R[i].y); w.y = cvtpk(R[i].z, R[i].w);
                *(uint2*)(xd + xdst[i]) = w;
            }
    };
    auto wd = [&](int s) {                    // W slot DMA: 288 quads, waves 0-4
        if (t < 288)
            gl2lds16((const float*)(wsrc0 + s * 32),
                     (float*)(&wsl[s % 3][0]) + t * 4);
    };

    // ---- acc init ----
    f32x4 acc[5];
#pragma unroll
    for (int mt = 0; mt < 5; ++mt)
#pragma unroll
        for (int r = 0; r < 4; ++r)
            acc[mt][r] = bcomb[mt * 16 + q * 4 + r];

    auto gemm = [&](int s) {
        const unsigned short* xpb = xper + (s * 32 + q * 8) * 216 + bqoff;
        union { short8 v; unsigned short u16[8]; } bq;
#pragma unroll
        for (int j = 0; j < 8; ++j)           // ch = s*32 + q*8 + j at px nb
            bq.u16[j] = xpb[j * 216];
        const unsigned short* wp = &wsl[s % 3][0];
#pragma unroll
        for (int mt = 0; mt < 5; ++mt) {
            const int m = mt * 16 + l15;
            const unsigned short* ap = (m < MM) ? (wp + m * 32 + aBo2) : wz;
            const short8 aq = *(const short8*)ap;
            acc[mt] = __builtin_amdgcn_mfma_f32_16x16x32_bf16(aq, bq.v, acc[mt], 0, 0, 0);
        }
    };

    // ---- prologue ----
    xl(0, ra); CFENCE; wd(0); CFENCE; xl(1, rb); CFENCE; wd(1); CFENCE;
    if (t < 320) { WAITVM(5); } else if (t < 384) { WAITVM(4); } else { WAITVM(3); }
    cw(0, ra); CFENCE; xl(2, ra);
    if (t < 8) wz[t] = 0;
    LGKM0; blockbar();

    // ---- A section: 8 phases ----
    auto phase = [&](int s, f32x4* R) {
        gemm(s);
        if (s == 7) {                         // ker -> kl (rows 72..79 dropped)
#pragma unroll
            for (int mt = 0; mt < 5; ++mt)
#pragma unroll
                for (int r = 0; r < 4; ++r) {
                    const int m = mt * 16 + q * 4 + r;
                    if (m < MM) kl[m * 112 + nb] = f2b(acc[mt][r]);
                }
            LGKM0; blockbar();
            return;
        }
        if (s < 6) { if (t < 384) { WAITVM(4); } else { WAITVM(3); } }
        else       { WAITVM(0); }             // one-time tail drain
        cw(s + 1, R); CFENCE;
        if (s <= 5) { wd(s + 2); CFENCE; }
        if (s <= 4) xl(s + 3, R);
        LGKM0; blockbar();
    };
#pragma unroll 1
    for (int s2 = 0; s2 < 8; s2 += 2) { phase(s2, rb); phase(s2 + 1, ra); }

    // ---- B section: free-running apply (no barriers, no vmcnt) ----
    f32x4 kr[9];
#pragma unroll 1
    for (int g = 0; g < 8; ++g) {
        {   // taps for group g (verbatim structure)
            ushort4 krb[9];
#pragma unroll
            for (int kk = 0; kk < 9; ++kk)
                krb[kk] = *(const ushort4*)&kl[(g * 9 + kk) * 112 + rA * 28 + qA * 4];
#pragma unroll
            for (int kh = 0; kh < 3; ++kh) {
#pragma unroll
                for (int j = 0; j < 3; ++j) {
                    const int kk = kh * 3 + j;
                    kr[kk].x = b2f(krb[kk].x) * vmm[kh];
                    kr[kk].y = b2f(krb[kk].y) * vmm[kh];
                    kr[kk].z = b2f(krb[kk].z) * vmm[kh];
                    kr[kk].w = b2f(krb[kk].w) * vmm[kh];
                }
                kr[kh * 3 + 0].x *= lm;       // tap reads col c0+4qA-1
                kr[kh * 3 + 2].w *= rmm;      // tap reads col c0+4qA+4
            }
        }
#pragma unroll
        for (int gh = 0; gh < 2; ++gh) {
            const int ch = (g * 2 + gh) * 16 + chh;
            const unsigned short* xc = xper + ch * 216;
            f32x4 a = {0.f, 0.f, 0.f, 0.f};
#pragma unroll
            for (int kh = 0; kh < 3; ++kh) {
                const unsigned short* rp = xc + (rA + kh) * 36;
                const unsigned short s0 = rp[4 * qA + 3];          // w0
                const uint2 v = *(const uint2*)(rp + 4 * qA + 4);  // w1..w4
                const unsigned short s5 = rp[4 * qA + 8];          // w5
                const float w0 = b2f(s0);
                const float w1 = asf((unsigned)v.x << 16);
                const float w2 = asf(v.x & 0xffff0000u);
                const float w3 = asf((unsigned)v.y << 16);
                const float w4 = asf(v.y & 0xffff0000u);
                const float w5 = b2f(s5);
                const f32x4 k0v = kr[kh * 3 + 0];
                const f32x4 k1v = kr[kh * 3 + 1];
                const f32x4 k2v = kr[kh * 3 + 2];
                a.x = fmaf(k0v.x, w0, a.x); a.y = fmaf(k0v.y, w1, a.y);
                a.z = fmaf(k0v.z, w2, a.z); a.w = fmaf(k0v.w, w3, a.w);
                a.x = fmaf(k1v.x, w1, a.x); a.y = fmaf(k1v.y, w2, a.y);
                a.z = fmaf(k1v.z, w3, a.z); a.w = fmaf(k1v.w, w4, a.w);
                a.x = fmaf(k2v.x, w2, a.x); a.y = fmaf(k2v.y, w3, a.y);
                a.z = fmaf(k2v.z, w4, a.z); a.w = fmaf(k2v.w, w5, a.w);
            }
            float* ob = out + ((size_t)b * CC + ch) * HW
                      + (h0 + rA) * WW + c0 + qA * 4;
            *(f32x4*)ob = a;
        }
    }
}

// ---------------------------------------------------------------------------
extern "C" void kernel_launch(void* const* d_in, const int* in_sizes, int n_in,
                              void* d_out, int out_size, void* d_ws, size_t ws_size,
                              hipStream_t stream) {
    const float* x        = (const float*)d_in[0];
    const float* w_reduce = (const float*)d_in[1];
    const float* b_reduce = (const float*)d_in[2];
    const float* w_span   = (const float*)d_in[3];
    const float* b_span   = (const float*)d_in[4];
    float* out = (float*)d_out;

    char* ws = (char*)d_ws;
    unsigned short* wbf   = (unsigned short*)ws;              // 40960 B
    float*          bcomb = (float*)(ws + 40960);             // 320 B

    k0_combine<<<dim3(80, 4), 256, 0, stream>>>(w_reduce, b_reduce, w_span, b_span,
                                                wbf, bcomb);
    k_fused<<<dim3(448), 448, 0, stream>>>(x, wbf, bcomb, out);
}